// Round 5
// baseline (20.550 us; speedup 1.0000x reference)
//
#include <hip/hip_runtime.h>
#include <math.h>

// RoPE: out[b,h,s,:] = R[pos[s]] @ x[b,h,s,:], block-diagonal 2x2 rotations.
// Shapes fixed: B=4, H=16, S=2048, D=64. Output f32.
//
// R5 = R4 with the nontemporal builtins applied to clang native vector types
// (ext_vector_type) instead of HIP_vector_type structs (compile fix).
//
//  Phase A (pack): packed coefs [S][64] = {cos_k, -sin_k} pairs into d_ws
//    (512 KB, L2/L3-resident). 65536 threads, one sincos each.
//  Phase B (stream): out[t] = rot(coef[t & 32767], x[t]) — pure linear
//    streaming, no trig/LDS. coef reads repeat across 64 (b,h) slices ->
//    cache hits. x/out marked non-temporal so the 2x33.5 MB streams don't
//    evict the coef table.
//
// inv_freq_k = 10000^(-2k/64); out[2k] = c*x[2k] - s*x[2k+1];
// out[2k+1] = s*x[2k] + c*x[2k+1]. Error budget verified in R3 (absmax .0156).

#define ROPE_B 4
#define ROPE_H 16
#define ROPE_S 2048
#define ROPE_D 64
#define ROPE_D4 (ROPE_D / 4)
#define COEF4_MASK (ROPE_S * ROPE_D4 - 1)   // 32767

typedef float floatx4 __attribute__((ext_vector_type(4)));

__device__ __forceinline__ void fast_sincos(float ang, float* sp, float* cp) {
    float r = ang * 0.15915494309189535f;   // ang / 2pi
    r = r - floorf(r);                      // [0,1)
    const float a = r * 6.283185307179586f;
    *sp = __sinf(a);
    *cp = __cosf(a);
}

__global__ __launch_bounds__(256) void rope_pack_coef(
    const int* __restrict__ token_positions,
    float* __restrict__ coef)               // [S][64]: {c0,-s0,c1,-s1,...}
{
    const int j = blockIdx.x * 256 + threadIdx.x;   // 0 .. 65535
    const int s = j >> 5;                   // position row
    const int k = j & 31;                   // pair index

    const float pos = (float)token_positions[s];
    const float NL2T_32 = -0.41524101186092029f;    // -log2(10000)/32
    const float inv_freq = exp2f((float)k * NL2T_32);

    float sn, cs;
    fast_sincos(pos * inv_freq, &sn, &cs);

    float2 cm; cm.x = cs; cm.y = -sn;
    *(float2*)(coef + s * ROPE_D + 2 * k) = cm;
}

__global__ __launch_bounds__(256) void MyRoPE_8899172237935_kernel(
    const float* __restrict__ x,
    const float* __restrict__ coef,
    float* __restrict__ out)
{
    const int t = blockIdx.x * 256 + threadIdx.x;   // float4 index

    const floatx4 xv = __builtin_nontemporal_load((const floatx4*)x + t);
    const floatx4 cm = ((const floatx4*)coef)[t & COEF4_MASK];  // cached

    floatx4 o;
    o.x = cm.x * xv.x + cm.y * xv.y;   // c*x0 - s*x1
    o.y = cm.x * xv.y - cm.y * xv.x;   // c*x1 + s*x0
    o.z = cm.z * xv.z + cm.w * xv.w;
    o.w = cm.z * xv.w - cm.w * xv.z;
    __builtin_nontemporal_store(o, (floatx4*)out + t);
}

extern "C" void kernel_launch(void* const* d_in, const int* in_sizes, int n_in,
                              void* d_out, int out_size, void* d_ws, size_t ws_size,
                              hipStream_t stream) {
    const float* x = (const float*)d_in[0];
    const int* token_positions = (const int*)d_in[1];
    // d_in[2] (rotation_table) unused: coefficients recomputed in pack phase.
    float* out = (float*)d_out;
    float* coef = (float*)d_ws;             // 512 KB scratch

    rope_pack_coef<<<(ROPE_S * 32) / 256, 256, 0, stream>>>(token_positions, coef);

    const int total4 = ROPE_B * ROPE_H * ROPE_S * ROPE_D4;  // 2,097,152
    MyRoPE_8899172237935_kernel<<<total4 / 256, 256, 0, stream>>>(x, coef, out);
}

// Round 6
// 16.464 us; speedup vs baseline: 1.2482x; 1.2482x over previous
//
#include <hip/hip_runtime.h>
#include <math.h>

// RoPE: out[b,h,s,:] = R[pos[s]] @ x[b,h,s,:], block-diagonal 2x2 rotations.
// Shapes fixed: B=4, H=16, S=2048, D=64. Output f32.
//
// R6 = R3 (single fused kernel, in-register trig, linear streaming) + 4x trig
// amortization. Index identity: float4-index t and t + j*524288 share the
// same (s, d4) — they differ only in the (b,h) slice — so one thread computes
// the (cos,sin) pair once and applies it to 4 float4s from 4 linear streams.
// Grid = 2048 blocks = exactly 8 blocks/CU (single full-occupancy generation).
// All 4 loads issued before trig -> 4 outstanding 16B loads/lane hide HBM
// latency under the transcendentals.
//
// inv_freq_k = 10000^(-2k/64) = exp2(-k*log2(10000)/32)
// out[2k] = c*x[2k] - s*x[2k+1] ; out[2k+1] = s*x[2k] + c*x[2k+1]
// Error budget verified in R3/R5 (absmax 0.0156, threshold 0.11).

#define ROPE_B 4
#define ROPE_H 16
#define ROPE_S 2048
#define ROPE_D 64
#define ROPE_D4 (ROPE_D / 4)
#define TOTAL4 (ROPE_B * ROPE_H * ROPE_S * ROPE_D4)  // 2,097,152 float4
#define QUARTER (TOTAL4 / 4)                          // 524,288: 16 bh-slices

typedef float floatx4 __attribute__((ext_vector_type(4)));

__global__ __launch_bounds__(256) void MyRoPE_8899172237935_kernel(
    const float* __restrict__ x,
    const int* __restrict__ token_positions,
    float* __restrict__ out)
{
    const int t = blockIdx.x * 256 + threadIdx.x;     // 0 .. QUARTER-1

    const floatx4* __restrict__ xp = (const floatx4*)x;
    floatx4* __restrict__ op = (floatx4*)out;

    // 4 independent linear streams (same s,d4; bh offset by 16 per slice)
    floatx4 v0 = xp[t];
    floatx4 v1 = xp[t + QUARTER];
    floatx4 v2 = xp[t + 2 * QUARTER];
    floatx4 v3 = xp[t + 3 * QUARTER];

    const int d4 = t & (ROPE_D4 - 1);
    const int s  = (t >> 4) & (ROPE_S - 1);
    const float pos = (float)token_positions[s];

    const float NL2T_32 = -0.41524101186092029f;      // -log2(10000)/32
    const float k0 = (float)(2 * d4);
    const float if0 = exp2f(k0 * NL2T_32);
    const float if1 = exp2f((k0 + 1.0f) * NL2T_32);

    // sincos in revolutions with explicit reduction
    float r0 = pos * if0 * 0.15915494309189535f; r0 -= floorf(r0);
    float r1 = pos * if1 * 0.15915494309189535f; r1 -= floorf(r1);
    const float a0 = r0 * 6.283185307179586f;
    const float a1 = r1 * 6.283185307179586f;
    const float s0 = __sinf(a0), c0 = __cosf(a0);
    const float s1 = __sinf(a1), c1 = __cosf(a1);

    #define ROT(vv, idx)                                   \
    {                                                      \
        floatx4 o;                                         \
        o.x = c0 * vv.x - s0 * vv.y;                       \
        o.y = s0 * vv.x + c0 * vv.y;                       \
        o.z = c1 * vv.z - s1 * vv.w;                       \
        o.w = s1 * vv.z + c1 * vv.w;                       \
        op[idx] = o;                                       \
    }
    ROT(v0, t)
    ROT(v1, t + QUARTER)
    ROT(v2, t + 2 * QUARTER)
    ROT(v3, t + 3 * QUARTER)
    #undef ROT
}

extern "C" void kernel_launch(void* const* d_in, const int* in_sizes, int n_in,
                              void* d_out, int out_size, void* d_ws, size_t ws_size,
                              hipStream_t stream) {
    const float* x = (const float*)d_in[0];
    const int* token_positions = (const int*)d_in[1];
    // d_in[2] (rotation_table) unused: coefficients recomputed in-register.
    float* out = (float*)d_out;

    MyRoPE_8899172237935_kernel<<<QUARTER / 256, 256, 0, stream>>>(x, token_positions, out);
}

// Round 7
// 15.343 us; speedup vs baseline: 1.3394x; 1.0731x over previous
//
#include <hip/hip_runtime.h>
#include <math.h>

// RoPE: out[b,h,s,:] = R[pos[s]] @ x[b,h,s,:], block-diagonal 2x2 rotations.
// Shapes fixed: B=4, H=16, S=2048, D=64. Output f32.
//
// R7: single-generation contiguous-block layout.
//   2048 blocks x 256 threads = exactly 8 blocks/CU (one dispatch generation,
//   no churn). Block b owns float4 range [b*1024, (b+1)*1024) — a contiguous
//   64 KB region. Thread handles indices t0 + {0,256,512,768} (stride keeps
//   wave accesses coalesced; each wave-iteration covers a contiguous 4 KB).
//   All 4 loads issued upfront -> 4-deep memory-level parallelism per lane.
//   Stride 256 preserves d4 = t & 15 -> exp2f computed once; s advances by 16
//   per iteration -> pos/sincos recomputed (VALU-hidden, proven by R6 null).
//
// inv_freq_k = 10000^(-2k/64) = exp2(-k*log2(10000)/32)
// out[2k] = c*x[2k] - s*x[2k+1] ; out[2k+1] = s*x[2k] + c*x[2k+1]
// Error budget verified R3/R5/R6 (absmax 0.0156, threshold 0.11).

#define ROPE_S 2048
#define ROPE_D4 16
#define TOTAL4 2097152            // B*H*S*D/4 float4 elements
#define NBLK 2048
#define PERBLK (TOTAL4 / NBLK)    // 1024 float4 per block

typedef float floatx4 __attribute__((ext_vector_type(4)));

__global__ __launch_bounds__(256) void MyRoPE_8899172237935_kernel(
    const float* __restrict__ x,
    const int* __restrict__ token_positions,
    float* __restrict__ out)
{
    const int t0 = blockIdx.x * PERBLK + threadIdx.x;

    const floatx4* __restrict__ xp = (const floatx4*)x;
    floatx4* __restrict__ op = (floatx4*)out;

    // 4-deep MLP: all loads in flight before any compute
    floatx4 v0 = xp[t0];
    floatx4 v1 = xp[t0 + 256];
    floatx4 v2 = xp[t0 + 512];
    floatx4 v3 = xp[t0 + 768];

    const int d4 = t0 & (ROPE_D4 - 1);                 // invariant across iters
    const float NL2T_32 = -0.41524101186092029f;       // -log2(10000)/32
    const float k0 = (float)(2 * d4);
    const float if0 = exp2f(k0 * NL2T_32);
    const float if1 = exp2f((k0 + 1.0f) * NL2T_32);

    const float INV2PI = 0.15915494309189535f;
    const float TWOPI  = 6.283185307179586f;

    #define ROT(vv, idx)                                                  \
    {                                                                     \
        const int s_ = ((idx) >> 4) & (ROPE_S - 1);                       \
        const float pos_ = (float)token_positions[s_];                    \
        float r0_ = pos_ * if0 * INV2PI; r0_ -= floorf(r0_);              \
        float r1_ = pos_ * if1 * INV2PI; r1_ -= floorf(r1_);              \
        const float a0_ = r0_ * TWOPI, a1_ = r1_ * TWOPI;                 \
        const float s0_ = __sinf(a0_), c0_ = __cosf(a0_);                 \
        const float s1_ = __sinf(a1_), c1_ = __cosf(a1_);                 \
        floatx4 o;                                                        \
        o.x = c0_ * vv.x - s0_ * vv.y;                                    \
        o.y = s0_ * vv.x + c0_ * vv.y;                                    \
        o.z = c1_ * vv.z - s1_ * vv.w;                                    \
        o.w = s1_ * vv.z + c1_ * vv.w;                                    \
        op[idx] = o;                                                      \
    }
    ROT(v0, t0)
    ROT(v1, t0 + 256)
    ROT(v2, t0 + 512)
    ROT(v3, t0 + 768)
    #undef ROT
}

extern "C" void kernel_launch(void* const* d_in, const int* in_sizes, int n_in,
                              void* d_out, int out_size, void* d_ws, size_t ws_size,
                              hipStream_t stream) {
    const float* x = (const float*)d_in[0];
    const int* token_positions = (const int*)d_in[1];
    // d_in[2] (rotation_table) unused: coefficients recomputed in-register.
    float* out = (float*)d_out;

    MyRoPE_8899172237935_kernel<<<NBLK, 256, 0, stream>>>(x, token_positions, out);
}